// Round 1
// baseline (10106.260 us; speedup 1.0000x reference)
//
#include <hip/hip_runtime.h>
#include <hip/hip_bf16.h>

// Problem constants
#define BDIM 8
#define TDIM 2048
#define CDIM 1024
#define HDIM 4096
#define EDIM 8
#define CAPACITY 320
#define MTOK (BDIM*TDIM)          // 16384
#define MCHUNK 2048               // router M-chunk
#define NCHUNKS (MTOK/MCHUNK)     // 8
#define EROWS (BDIM*CAPACITY)     // 2560 rows per expert
#define NROWS (EDIM*EROWS)        // 20480 total slots

typedef __attribute__((ext_vector_type(8))) short bf16x8;
typedef __attribute__((ext_vector_type(4))) float f32x4;

__device__ __forceinline__ unsigned short f2bf(float f){
    __hip_bfloat16 h = __float2bfloat16(f);
    return *reinterpret_cast<unsigned short*>(&h);
}

// ---------------------------------------------------------------------------
// K0: transpose + fp32->bf16 convert.  in: [z][R][Ccol] f32, out: [z][Ccol][R] bf16
// grid: (Ccol/32, R/32, Z), block 256
// ---------------------------------------------------------------------------
__global__ __launch_bounds__(256) void transpose_convert(
    const float* __restrict__ in, unsigned short* __restrict__ out, int R, int Ccol)
{
    int z = blockIdx.z;
    in  += (size_t)z * R * Ccol;
    out += (size_t)z * R * Ccol;
    __shared__ float tile[32][33];
    int r0 = blockIdx.y * 32, c0 = blockIdx.x * 32;
    int tid = threadIdx.x;
    int lr = tid >> 5, lc = tid & 31;
    #pragma unroll
    for (int it = 0; it < 4; it++)
        tile[it*8 + lr][lc] = in[(size_t)(r0 + it*8 + lr) * Ccol + c0 + lc];
    __syncthreads();
    #pragma unroll
    for (int it = 0; it < 4; it++){
        float v = tile[lc][it*8 + lr];
        out[(size_t)(c0 + it*8 + lr) * R + r0 + lc] = f2bf(v);
    }
}

// ---------------------------------------------------------------------------
// K1/K2: fp32 tiled GEMM  C = act(A[M,K] @ B[K,N] + bias[N])
// 128x128 tile, BK=8, 256 threads, 8x8 micro-tile. grid (N/128, M/128)
// ---------------------------------------------------------------------------
__global__ __launch_bounds__(256) void gemm_f32(
    const float* __restrict__ A, const float* __restrict__ B,
    const float* __restrict__ bias, float* __restrict__ C,
    int M, int N, int K, int doRelu)
{
    __shared__ float As[8][128];   // transposed [k][m]
    __shared__ float Bs[8][128];   // [k][n]
    int tid = threadIdx.x;
    int m0 = blockIdx.y * 128, n0 = blockIdx.x * 128;
    int tx = tid & 15, ty = tid >> 4;
    float acc[8][8];
    #pragma unroll
    for (int i = 0; i < 8; i++)
        #pragma unroll
        for (int j = 0; j < 8; j++) acc[i][j] = 0.f;

    int arow = tid >> 1, ak = (tid & 1) * 4;   // A staging: 128 rows x 8k
    int bk = tid >> 5,  bn = (tid & 31) * 4;   // B staging: 8k x 128n

    for (int k0 = 0; k0 < K; k0 += 8){
        float4 av = *(const float4*)(A + (size_t)(m0 + arow) * K + k0 + ak);
        float4 bv = *(const float4*)(B + (size_t)(k0 + bk) * N + n0 + bn);
        __syncthreads();
        As[ak+0][arow] = av.x; As[ak+1][arow] = av.y;
        As[ak+2][arow] = av.z; As[ak+3][arow] = av.w;
        *(float4*)&Bs[bk][bn] = bv;
        __syncthreads();
        #pragma unroll
        for (int kk = 0; kk < 8; kk++){
            float a[8], b[8];
            *(float4*)(a+0) = *(const float4*)&As[kk][ty*4];
            *(float4*)(a+4) = *(const float4*)&As[kk][ty*4 + 64];
            *(float4*)(b+0) = *(const float4*)&Bs[kk][tx*4];
            *(float4*)(b+4) = *(const float4*)&Bs[kk][tx*4 + 64];
            #pragma unroll
            for (int i = 0; i < 8; i++)
                #pragma unroll
                for (int j = 0; j < 8; j++)
                    acc[i][j] = fmaf(a[i], b[j], acc[i][j]);
        }
    }
    #pragma unroll
    for (int i = 0; i < 8; i++){
        int m = m0 + ty*4 + (i < 4 ? i : 64 + (i - 4));
        float* Crow = C + (size_t)m * N;
        #pragma unroll
        for (int jh = 0; jh < 2; jh++){
            int n = n0 + tx*4 + jh*64;
            float4 bv = *(const float4*)(bias + n);
            float4 v;
            v.x = acc[i][jh*4+0] + bv.x;
            v.y = acc[i][jh*4+1] + bv.y;
            v.z = acc[i][jh*4+2] + bv.z;
            v.w = acc[i][jh*4+3] + bv.w;
            if (doRelu){
                v.x = fmaxf(v.x, 0.f); v.y = fmaxf(v.y, 0.f);
                v.z = fmaxf(v.z, 0.f); v.w = fmaxf(v.w, 0.f);
            }
            *(float4*)(Crow + n) = v;
        }
    }
}

// ---------------------------------------------------------------------------
// K3: router head. logits = h2 @ rW3 + rb3; softmax (double); top-2 w/ tie->low idx
// block = 256 threads = 32 tokens x 8 experts. grid = MCHUNK/32
// ---------------------------------------------------------------------------
__global__ __launch_bounds__(256) void router_head(
    const float* __restrict__ h2, const float* __restrict__ W3,
    const float* __restrict__ b3, int tokBase,
    int* __restrict__ top2e, float* __restrict__ top2s)
{
    int tid = threadIdx.x;
    int tloc = blockIdx.x * 32 + (tid >> 3);
    int e = tid & 7;
    const float* hrow = h2 + (size_t)tloc * HDIM;
    float acc = 0.f;
    for (int k = 0; k < HDIM; k += 4){
        float4 h = *(const float4*)(hrow + k);
        acc = fmaf(h.x, W3[(k+0)*8 + e], acc);
        acc = fmaf(h.y, W3[(k+1)*8 + e], acc);
        acc = fmaf(h.z, W3[(k+2)*8 + e], acc);
        acc = fmaf(h.w, W3[(k+3)*8 + e], acc);
    }
    float logit = acc + b3[e];
    __shared__ float lg[32][8];
    lg[tid >> 3][e] = logit;
    __syncthreads();
    if (tid < 32){
        double l[8];
        double mx = -1e300;
        for (int i = 0; i < 8; i++){ l[i] = (double)lg[tid][i]; if (l[i] > mx) mx = l[i]; }
        double ex[8]; double s = 0.0;
        for (int i = 0; i < 8; i++){ ex[i] = exp(l[i] - mx); s += ex[i]; }
        double b1v = -1.0, b2v = -1.0; int e1 = 0, e2 = 0;
        for (int i = 0; i < 8; i++){
            double v = ex[i];
            if (v > b1v){ b2v = b1v; e2 = e1; b1v = v; e1 = i; }
            else if (v > b2v){ b2v = v; e2 = i; }
        }
        int gt = tokBase + blockIdx.x * 32 + tid;
        top2e[gt*2 + 0] = e1;
        top2e[gt*2 + 1] = e2;
        top2s[gt*2 + 0] = (float)(b1v / s);
        top2s[gt*2 + 1] = (float)(b2v / s);
    }
}

// ---------------------------------------------------------------------------
// K4: dispatch scan. One block per batch row b. Exact (t, slot) cumsum order.
// ---------------------------------------------------------------------------
__global__ __launch_bounds__(256) void scan_dispatch(
    const int* __restrict__ top2e, int* __restrict__ slot_row, int* __restrict__ row2tok)
{
    int b = blockIdx.x;
    int tid = threadIdx.x;
    __shared__ int cnt[256][8];
    int base = b * (TDIM * 2);
    int i0 = tid * 16;
    int c[8];
    #pragma unroll
    for (int e = 0; e < 8; e++) c[e] = 0;
    for (int j = 0; j < 16; j++){
        int e = top2e[base + i0 + j];
        c[e]++;
    }
    #pragma unroll
    for (int e = 0; e < 8; e++) cnt[tid][e] = c[e];
    __syncthreads();
    if (tid < 8){
        int run = 0;
        for (int t = 0; t < 256; t++){ int v = cnt[t][tid]; cnt[t][tid] = run; run += v; }
    }
    __syncthreads();
    int offs[8];
    #pragma unroll
    for (int e = 0; e < 8; e++) offs[e] = cnt[tid][e];
    for (int j = 0; j < 16; j++){
        int i = i0 + j;
        int e = top2e[base + i];
        int pos = offs[e]++;
        int r = (pos < CAPACITY) ? ((e * BDIM + b) * CAPACITY + pos) : -1;
        slot_row[base + i] = r;
        if (r >= 0) row2tok[r] = b * TDIM + (i >> 1);
    }
}

// ---------------------------------------------------------------------------
// K5: gather tokens into expert slot buffer (bf16). One block per slot row.
// ---------------------------------------------------------------------------
__global__ __launch_bounds__(256) void gather_rows(
    const float* __restrict__ x, const int* __restrict__ row2tok,
    unsigned short* __restrict__ Xe)
{
    int r = blockIdx.x;
    int tid = threadIdx.x;
    int tok = row2tok[r];
    unsigned short* dst = Xe + (size_t)r * CDIM + tid * 4;
    if (tok >= 0){
        float4 v = *(const float4*)(x + (size_t)tok * CDIM + tid * 4);
        ushort4 o;
        o.x = f2bf(v.x); o.y = f2bf(v.y); o.z = f2bf(v.z); o.w = f2bf(v.w);
        *(ushort4*)dst = o;
    } else {
        ushort4 o; o.x = o.y = o.z = o.w = 0;
        *(ushort4*)dst = o;
    }
}

// ---------------------------------------------------------------------------
// K6/K7: bf16 MFMA GEMM.  out = act(A[M,K] @ Bt[N,K]^T + bias[N])
// 64x64 tile, BK=32, 256 threads (4 waves, each 32x32 via 2x2 mfma 16x16x32).
// mode 0: relu -> bf16 out (hidden).  mode 1: plain -> f32 out.
// grid (M/64, N/64)
// ---------------------------------------------------------------------------
__global__ __launch_bounds__(256) void gemm_bf16_mfma(
    const unsigned short* __restrict__ A, const unsigned short* __restrict__ Bt,
    const float* __restrict__ bias, void* __restrict__ outv,
    int M, int N, int K, int mode)
{
    __shared__ unsigned short As[64 * 40];   // [m][k] pad to 40 (80B rows, 16B-aligned)
    __shared__ unsigned short Bs[64 * 40];   // [n][k]
    int tid = threadIdx.x;
    int m0 = blockIdx.x * 64, n0 = blockIdx.y * 64;
    int lane = tid & 63, w = tid >> 6;
    int wm = w & 1, wn = w >> 1;
    int l15 = lane & 15, quad = lane >> 4;

    f32x4 acc[2][2];
    #pragma unroll
    for (int a = 0; a < 2; a++)
        #pragma unroll
        for (int bq = 0; bq < 2; bq++){ acc[a][bq].x=0.f; acc[a][bq].y=0.f; acc[a][bq].z=0.f; acc[a][bq].w=0.f; }

    int srow = tid >> 2, sseg = (tid & 3) * 8;
    const unsigned short* Ap = A + (size_t)(m0 + srow) * K + sseg;
    const unsigned short* Bp = Bt + (size_t)(n0 + srow) * K + sseg;
    unsigned short* Aw = As + srow * 40 + sseg;
    unsigned short* Bw = Bs + srow * 40 + sseg;

    for (int k0 = 0; k0 < K; k0 += 32){
        uint4 av = *(const uint4*)(Ap + k0);
        uint4 bv = *(const uint4*)(Bp + k0);
        __syncthreads();
        *(uint4*)Aw = av;
        *(uint4*)Bw = bv;
        __syncthreads();
        bf16x8 af0 = *(const bf16x8*)(As + (wm*32 +  0 + l15) * 40 + quad*8);
        bf16x8 af1 = *(const bf16x8*)(As + (wm*32 + 16 + l15) * 40 + quad*8);
        bf16x8 bf0 = *(const bf16x8*)(Bs + (wn*32 +  0 + l15) * 40 + quad*8);
        bf16x8 bf1 = *(const bf16x8*)(Bs + (wn*32 + 16 + l15) * 40 + quad*8);
        acc[0][0] = __builtin_amdgcn_mfma_f32_16x16x32_bf16(af0, bf0, acc[0][0], 0, 0, 0);
        acc[0][1] = __builtin_amdgcn_mfma_f32_16x16x32_bf16(af0, bf1, acc[0][1], 0, 0, 0);
        acc[1][0] = __builtin_amdgcn_mfma_f32_16x16x32_bf16(af1, bf0, acc[1][0], 0, 0, 0);
        acc[1][1] = __builtin_amdgcn_mfma_f32_16x16x32_bf16(af1, bf1, acc[1][1], 0, 0, 0);
    }

    #pragma unroll
    for (int mt = 0; mt < 2; mt++)
        #pragma unroll
        for (int nt = 0; nt < 2; nt++){
            int mb = m0 + wm*32 + mt*16 + quad*4;
            int n  = n0 + wn*32 + nt*16 + l15;
            float bz = bias[n];
            #pragma unroll
            for (int r = 0; r < 4; r++){
                float v = acc[mt][nt][r] + bz;
                int m = mb + r;
                if (mode == 0){
                    v = fmaxf(v, 0.f);
                    ((unsigned short*)outv)[(size_t)m * N + n] = f2bf(v);
                } else {
                    ((float*)outv)[(size_t)m * N + n] = v;
                }
            }
        }
}

// ---------------------------------------------------------------------------
// K8: combine. out[b,t,:] = s1*eout[r1,:] + s2*eout[r2,:] (dropped -> 0)
// one block per token
// ---------------------------------------------------------------------------
__global__ __launch_bounds__(256) void combine(
    const float* __restrict__ eout, const int* __restrict__ slot_row,
    const float* __restrict__ top2s, float* __restrict__ out)
{
    int gt = blockIdx.x;
    int b = gt >> 11, t = gt & (TDIM - 1);
    int i = b * (TDIM * 2) + t * 2;
    int r1 = slot_row[i], r2 = slot_row[i + 1];
    float s1 = top2s[gt*2 + 0], s2 = top2s[gt*2 + 1];
    int c = threadIdx.x * 4;
    float4 acc; acc.x = acc.y = acc.z = acc.w = 0.f;
    if (r1 >= 0){
        float4 v = *(const float4*)(eout + (size_t)r1 * CDIM + c);
        acc.x = fmaf(s1, v.x, acc.x); acc.y = fmaf(s1, v.y, acc.y);
        acc.z = fmaf(s1, v.z, acc.z); acc.w = fmaf(s1, v.w, acc.w);
    }
    if (r2 >= 0){
        float4 v = *(const float4*)(eout + (size_t)r2 * CDIM + c);
        acc.x = fmaf(s2, v.x, acc.x); acc.y = fmaf(s2, v.y, acc.y);
        acc.z = fmaf(s2, v.z, acc.z); acc.w = fmaf(s2, v.w, acc.w);
    }
    *(float4*)(out + (size_t)gt * CDIM + c) = acc;
}

// ---------------------------------------------------------------------------
extern "C" void kernel_launch(void* const* d_in, const int* in_sizes, int n_in,
                              void* d_out, int out_size, void* d_ws, size_t ws_size,
                              hipStream_t stream)
{
    const float* x   = (const float*)d_in[0];
    const float* rW1 = (const float*)d_in[1];
    const float* rb1 = (const float*)d_in[2];
    const float* rW2 = (const float*)d_in[3];
    const float* rb2 = (const float*)d_in[4];
    const float* rW3 = (const float*)d_in[5];
    const float* rb3 = (const float*)d_in[6];
    const float* eW1 = (const float*)d_in[7];
    const float* eb1 = (const float*)d_in[8];
    const float* eW2 = (const float*)d_in[9];
    const float* eb2 = (const float*)d_in[10];
    float* out = (float*)d_out;

    // workspace carve-up (all 256B aligned)
    char* p = (char*)d_ws;
    auto alloc = [&](size_t bytes) -> void* {
        void* q = (void*)p;
        p += (bytes + 255) & ~(size_t)255;
        return q;
    };
    float*          h1c   = (float*)alloc((size_t)MCHUNK * HDIM * 4);          // 33.5 MB
    float*          h2c   = (float*)alloc((size_t)MCHUNK * HDIM * 4);          // 33.5 MB
    int*            top2e = (int*)alloc((size_t)MTOK * 2 * 4);
    float*          top2s = (float*)alloc((size_t)MTOK * 2 * 4);
    int*            slotr = (int*)alloc((size_t)BDIM * TDIM * 2 * 4);
    int*            r2tok = (int*)alloc((size_t)NROWS * 4);
    unsigned short* Xe    = (unsigned short*)alloc((size_t)NROWS * CDIM * 2);  // 42 MB
    unsigned short* He    = (unsigned short*)alloc((size_t)EROWS * HDIM * 2);  // 21 MB (per-expert reuse)
    float*          eout  = (float*)alloc((size_t)NROWS * CDIM * 4);           // 84 MB
    unsigned short* eW1t  = (unsigned short*)alloc((size_t)EDIM * HDIM * CDIM * 2); // 67 MB  [e][H][C]
    unsigned short* eW2t  = (unsigned short*)alloc((size_t)EDIM * CDIM * HDIM * 2); // 67 MB  [e][C][H]

    // 1) expert weights -> bf16, transposed to [N][K]
    transpose_convert<<<dim3(HDIM/32, CDIM/32, EDIM), 256, 0, stream>>>(eW1, eW1t, CDIM, HDIM);
    transpose_convert<<<dim3(CDIM/32, HDIM/32, EDIM), 256, 0, stream>>>(eW2, eW2t, HDIM, CDIM);

    // 2) router, chunked over tokens
    for (int mc = 0; mc < NCHUNKS; mc++){
        const float* xA = x + (size_t)mc * MCHUNK * CDIM;
        gemm_f32<<<dim3(HDIM/128, MCHUNK/128), 256, 0, stream>>>(xA,  rW1, rb1, h1c, MCHUNK, HDIM, CDIM, 1);
        gemm_f32<<<dim3(HDIM/128, MCHUNK/128), 256, 0, stream>>>(h1c, rW2, rb2, h2c, MCHUNK, HDIM, HDIM, 1);
        router_head<<<MCHUNK/32, 256, 0, stream>>>(h2c, rW3, rb3, mc * MCHUNK, top2e, top2s);
    }

    // 3) dispatch
    hipMemsetAsync(r2tok, 0xFF, (size_t)NROWS * 4, stream);
    scan_dispatch<<<BDIM, 256, 0, stream>>>(top2e, slotr, r2tok);
    gather_rows<<<NROWS, 256, 0, stream>>>(x, r2tok, Xe);

    // 4) expert FFNs (bf16 MFMA), per-expert to reuse He
    for (int e = 0; e < EDIM; e++){
        const unsigned short* Ae  = Xe   + (size_t)e * EROWS * CDIM;
        const unsigned short* B1  = eW1t + (size_t)e * HDIM * CDIM;
        const unsigned short* B2  = eW2t + (size_t)e * CDIM * HDIM;
        const float*          bz1 = eb1  + (size_t)e * HDIM;
        const float*          bz2 = eb2  + (size_t)e * CDIM;
        float*                Oe  = eout + (size_t)e * EROWS * CDIM;
        gemm_bf16_mfma<<<dim3(EROWS/64, HDIM/64), 256, 0, stream>>>(Ae, B1, bz1, (void*)He, EROWS, HDIM, CDIM, 0);
        gemm_bf16_mfma<<<dim3(EROWS/64, CDIM/64), 256, 0, stream>>>(He, B2, bz2, (void*)Oe, EROWS, CDIM, HDIM, 1);
    }

    // 5) combine
    combine<<<MTOK, 256, 0, stream>>>(eout, slotr, top2s, out);
}